// Round 1
// baseline (48.378 us; speedup 1.0000x reference)
//
#include <hip/hip_runtime.h>
#include <math.h>

// Problem constants (from reference setup_inputs): B=32, C=1, H=W=512, f32.
constexpr int IMG_W = 512;
constexpr int IMG_H = 512;
constexpr int BATCH = 32;
constexpr int NPIX  = BATCH * IMG_H * IMG_W;   // 8388608
constexpr int NVEC  = NPIX / 4;                // 2097152 float4s
constexpr int NBLK  = 2048;
constexpr int NTHR  = 256;
constexpr int NACC  = 8;  // l1, sum(p*t), sum(p), sum(t), gx, gy, dil, ero

// Kernel 1: fused map + per-block reduction of all 8 partial sums.
__global__ __launch_bounds__(NTHR) void morph_partials(
    const float* __restrict__ pred, const float* __restrict__ tgt,
    float* __restrict__ ws)
{
    float a[NACC];
#pragma unroll
    for (int k = 0; k < NACC; ++k) a[k] = 0.f;

    const int stride = NBLK * NTHR;
    for (int v = blockIdx.x * NTHR + threadIdx.x; v < NVEC; v += stride) {
        const int i = v << 2;                 // flat pixel index of lane's first pixel
        const int x = i & (IMG_W - 1);        // 0..508, multiple of 4
        const int y = (i >> 9) & (IMG_H - 1); // row within the image

        const float4 pC = *(const float4*)(pred + i);
        const float4 tC = *(const float4*)(tgt + i);
        float pc[4] = {pC.x, pC.y, pC.z, pC.w};
        float tc[4] = {tC.x, tC.y, tC.z, tC.w};

        float pu[4] = {0.f, 0.f, 0.f, 0.f}, tu[4] = {0.f, 0.f, 0.f, 0.f};
        float pd[4] = {0.f, 0.f, 0.f, 0.f}, td[4] = {0.f, 0.f, 0.f, 0.f};
        const bool hasU = (y > 0);
        const bool hasD = (y < IMG_H - 1);
        if (hasU) {
            const float4 u1 = *(const float4*)(pred + i - IMG_W);
            const float4 u2 = *(const float4*)(tgt  + i - IMG_W);
            pu[0] = u1.x; pu[1] = u1.y; pu[2] = u1.z; pu[3] = u1.w;
            tu[0] = u2.x; tu[1] = u2.y; tu[2] = u2.z; tu[3] = u2.w;
        }
        if (hasD) {
            const float4 d1 = *(const float4*)(pred + i + IMG_W);
            const float4 d2 = *(const float4*)(tgt  + i + IMG_W);
            pd[0] = d1.x; pd[1] = d1.y; pd[2] = d1.z; pd[3] = d1.w;
            td[0] = d2.x; td[1] = d2.y; td[2] = d2.z; td[3] = d2.w;
        }

        float pl = 0.f, tl = 0.f, pr = 0.f, tr = 0.f;
        const bool hasL = (x > 0);
        const bool hasR = (x + 4 < IMG_W);
        if (hasL) { pl = pred[i - 1]; tl = tgt[i - 1]; }
        if (hasR) { pr = pred[i + 4]; tr = tgt[i + 4]; }

#pragma unroll
        for (int j = 0; j < 4; ++j) {
            const float pcj = pc[j], tcj = tc[j];
            // L1 + dice sums
            a[0] += fabsf(pcj - tcj);
            a[1] += pcj * tcj;
            a[2] += pcj;
            a[3] += tcj;
            // x-gradient pairs fully inside the vector
            if (j < 3)
                a[4] += fabsf(fabsf(pc[j + 1] - pcj) - fabsf(tc[j + 1] - tcj));
            // cross-SE neighbors (zero-padded at image borders)
            const float plj = j ? pc[j - 1] : pl;
            const float prj = (j < 3) ? pc[j + 1] : pr;
            const float tlj = j ? tc[j - 1] : tl;
            const float trj = (j < 3) ? tc[j + 1] : tr;
            // dilation: 1 - prod(1 - neighbor)
            float dp = 1.f - (1.f - pcj) * (1.f - plj) * (1.f - prj) * (1.f - pu[j]) * (1.f - pd[j]);
            float dt = 1.f - (1.f - tcj) * (1.f - tlj) * (1.f - trj) * (1.f - tu[j]) * (1.f - td[j]);
            dp = fminf(fmaxf(dp, 0.f), 1.f);
            dt = fminf(fmaxf(dt, 0.f), 1.f);
            a[6] += fabsf(dp - dt);
            // erosion: prod(neighbor), OOB -> 0
            float ep = pcj * plj * prj * pu[j] * pd[j];
            float et = tcj * tlj * trj * tu[j] * td[j];
            ep = fminf(fmaxf(ep, 0.f), 1.f);
            et = fminf(fmaxf(et, 0.f), 1.f);
            a[7] += fabsf(ep - et);
        }
        // x-gradient pair (x+3, x+4) across the vector boundary
        if (hasR)
            a[4] += fabsf(fabsf(pr - pc[3]) - fabsf(tr - tc[3]));
        // y-gradient pairs (y, y+1)
        if (hasD) {
#pragma unroll
            for (int j = 0; j < 4; ++j)
                a[5] += fabsf(fabsf(pd[j] - pc[j]) - fabsf(td[j] - tc[j]));
        }
    }

    // Block reduction: wave shuffle then LDS across 4 waves.
    __shared__ float sm[NACC][NTHR / 64];
#pragma unroll
    for (int k = 0; k < NACC; ++k) {
        float v = a[k];
        for (int o = 32; o > 0; o >>= 1) v += __shfl_down(v, o, 64);
        if ((threadIdx.x & 63) == 0) sm[k][threadIdx.x >> 6] = v;
    }
    __syncthreads();
    if (threadIdx.x < NACC) {
        float v = 0.f;
#pragma unroll
        for (int w = 0; w < NTHR / 64; ++w) v += sm[threadIdx.x][w];
        ws[threadIdx.x * NBLK + blockIdx.x] = v;  // layout [acc][block]
    }
}

// Kernel 2: one block reduces the per-block partials (in double) and applies
// the loss formula.
__global__ __launch_bounds__(NTHR) void morph_final(
    const float* __restrict__ ws, float* __restrict__ out)
{
    __shared__ double sm[NACC][NTHR / 64];
#pragma unroll
    for (int k = 0; k < NACC; ++k) {
        double v = 0.0;
        for (int idx = threadIdx.x; idx < NBLK; idx += NTHR)
            v += (double)ws[k * NBLK + idx];
        for (int o = 32; o > 0; o >>= 1) v += __shfl_down(v, o, 64);
        if ((threadIdx.x & 63) == 0) sm[k][threadIdx.x >> 6] = v;
    }
    __syncthreads();
    if (threadIdx.x == 0) {
        double r[NACC];
#pragma unroll
        for (int k = 0; k < NACC; ++k) {
            double s = 0.0;
            for (int w = 0; w < NTHR / 64; ++w) s += sm[k][w];
            r[k] = s;
        }
        const double Npix  = (double)NPIX;                       // 8388608
        const double Ngrad = (double)BATCH * IMG_H * (IMG_W - 1); // 8372224 (same for x and y)

        double total = r[0] / Npix;  // reconstruction L1
        // dice
        double dice = (2.0 * r[1] + 1e-5) / (r[2] + r[3] + 1e-5);
        dice = fmin(fmax(dice, 0.0), 1.0);
        total += 0.3 * (-log(dice + 1e-8));
        // boundary
        total += 0.2 * 0.5 * ((r[4] + r[5]) / Ngrad);
        // morphological
        total += 0.2 * 0.5 * ((r[6] + r[7]) / Npix);

        out[0] = (float)fmax(total, 0.0);
    }
}

extern "C" void kernel_launch(void* const* d_in, const int* in_sizes, int n_in,
                              void* d_out, int out_size, void* d_ws, size_t ws_size,
                              hipStream_t stream) {
    const float* pred = (const float*)d_in[0];
    const float* tgt  = (const float*)d_in[1];
    float* out = (float*)d_out;
    float* ws  = (float*)d_ws;   // needs NACC*NBLK*4 = 64 KB

    morph_partials<<<NBLK, NTHR, 0, stream>>>(pred, tgt, ws);
    morph_final<<<1, NTHR, 0, stream>>>(ws, out);
}

// Round 2
// 35.105 us; speedup vs baseline: 1.3781x; 1.3781x over previous
//
#include <hip/hip_runtime.h>
#include <math.h>

// Problem constants: B=32, C=1, H=W=512, f32 in/out scalar loss.
constexpr int IMG_W  = 512;
constexpr int IMG_H  = 512;
constexpr int BATCH  = 32;
constexpr int NPIX   = BATCH * IMG_H * IMG_W;   // 8388608
constexpr int NROWS  = BATCH * IMG_H;           // 16384
constexpr int RSTRIP = 8;                        // rows per unit
constexpr int NUNIT  = NROWS / RSTRIP;           // 2048 units of 128 threads
constexpr int NTHR   = 256;                      // 2 units per block
constexpr int NBLK   = NUNIT / 2;                // 1024 blocks
constexpr int NACC   = 8;  // l1, sum(p*t), sum(p), sum(t), gx, gy, dil, ero

__global__ __launch_bounds__(NTHR) void morph_partials(
    const float* __restrict__ pred, const float* __restrict__ tgt,
    float* __restrict__ ws)
{
    float a[NACC];
#pragma unroll
    for (int k = 0; k < NACC; ++k) a[k] = 0.f;

    const int unit    = blockIdx.x * 2 + (threadIdx.x >> 7); // 0..2047
    const int lane128 = threadIdx.x & 127;                   // float4 index in row
    const int lane64  = threadIdx.x & 63;
    const int g0      = unit * RSTRIP;                       // first global row
    const int img     = g0 >> 9;                             // /512 (strip within image)
    const int y0      = g0 & 511;
    const int imgbase = (img << 18) + (lane128 << 2);        // img*512*512 + x

    const float4 z4 = make_float4(0.f, 0.f, 0.f, 0.f);
    float4 pp, tp, pc, tc, pn, tn;

    // prev row (zero-pad at image top)
    if (y0 != 0) {
        const int idx = imgbase + ((y0 - 1) << 9);
        pp = *(const float4*)(pred + idx);
        tp = *(const float4*)(tgt  + idx);
    } else { pp = z4; tp = z4; }
    // current row
    {
        const int idx = imgbase + (y0 << 9);
        pc = *(const float4*)(pred + idx);
        tc = *(const float4*)(tgt  + idx);
    }

    for (int r = 0; r < RSTRIP; ++r) {
        const int y = y0 + r;
        const bool hasD = (y != IMG_H - 1);
        if (hasD) {
            const int idx = imgbase + ((y + 1) << 9);
            pn = *(const float4*)(pred + idx);
            tn = *(const float4*)(tgt  + idx);
        } else { pn = z4; tn = z4; }

        // horizontal neighbors via wave shuffle; fix up wave-boundary lanes
        float pl = __shfl_up(pc.w, 1, 64);
        float tl = __shfl_up(tc.w, 1, 64);
        float pr = __shfl_down(pc.x, 1, 64);
        float tr = __shfl_down(tc.x, 1, 64);
        const int i = imgbase + (y << 9);
        if (lane64 == 0) {
            if (lane128 == 0) { pl = 0.f; tl = 0.f; }
            else              { pl = pred[i - 1]; tl = tgt[i - 1]; }
        }
        if (lane64 == 63) {
            if (lane128 == 127) { pr = 0.f; tr = 0.f; }
            else                { pr = pred[i + 4]; tr = tgt[i + 4]; }
        }
        const bool hasR = (lane128 != 127);

        const float* pcA = &pc.x; const float* tcA = &tc.x;
        const float* ppA = &pp.x; const float* tpA = &tp.x;
        const float* pnA = &pn.x; const float* tnA = &tn.x;

#pragma unroll
        for (int j = 0; j < 4; ++j) {
            const float pcj = pcA[j], tcj = tcA[j];
            a[0] += fabsf(pcj - tcj);
            a[1] += pcj * tcj;
            a[2] += pcj;
            a[3] += tcj;
            if (j < 3)
                a[4] += fabsf(fabsf(pcA[j + 1] - pcj) - fabsf(tcA[j + 1] - tcj));
            const float plj = j ? pcA[j - 1] : pl;
            const float prj = (j < 3) ? pcA[j + 1] : pr;
            const float tlj = j ? tcA[j - 1] : tl;
            const float trj = (j < 3) ? tcA[j + 1] : tr;
            // dilation: 1 - prod(1 - neighbor), cross SE, zero-padded
            float dp = 1.f - (1.f - pcj) * (1.f - plj) * (1.f - prj) * (1.f - ppA[j]) * (1.f - pnA[j]);
            float dt = 1.f - (1.f - tcj) * (1.f - tlj) * (1.f - trj) * (1.f - tpA[j]) * (1.f - tnA[j]);
            dp = fminf(fmaxf(dp, 0.f), 1.f);
            dt = fminf(fmaxf(dt, 0.f), 1.f);
            a[6] += fabsf(dp - dt);
            // erosion: prod(neighbors), OOB -> 0
            float ep = pcj * plj * prj * ppA[j] * pnA[j];
            float et = tcj * tlj * trj * tpA[j] * tnA[j];
            ep = fminf(fmaxf(ep, 0.f), 1.f);
            et = fminf(fmaxf(et, 0.f), 1.f);
            a[7] += fabsf(ep - et);
        }
        // x-gradient pair crossing the float4 boundary
        if (hasR)
            a[4] += fabsf(fabsf(pr - pcA[3]) - fabsf(tr - tcA[3]));
        // y-gradient pairs (y, y+1)
        if (hasD) {
#pragma unroll
            for (int j = 0; j < 4; ++j)
                a[5] += fabsf(fabsf(pnA[j] - pcA[j]) - fabsf(tnA[j] - tcA[j]));
        }

        pp = pc; tp = tc; pc = pn; tc = tn;
    }

    // Block reduction: wave shuffle then LDS across 4 waves.
    __shared__ float sm[NACC][NTHR / 64];
#pragma unroll
    for (int k = 0; k < NACC; ++k) {
        float v = a[k];
        for (int o = 32; o > 0; o >>= 1) v += __shfl_down(v, o, 64);
        if ((threadIdx.x & 63) == 0) sm[k][threadIdx.x >> 6] = v;
    }
    __syncthreads();
    if (threadIdx.x < NACC) {
        float v = 0.f;
#pragma unroll
        for (int w = 0; w < NTHR / 64; ++w) v += sm[threadIdx.x][w];
        ws[threadIdx.x * NBLK + blockIdx.x] = v;  // layout [acc][block]
    }
}

// One block reduces the per-block partials (double) and applies the formula.
__global__ __launch_bounds__(NTHR) void morph_final(
    const float* __restrict__ ws, float* __restrict__ out)
{
    __shared__ double sm[NACC][NTHR / 64];
#pragma unroll
    for (int k = 0; k < NACC; ++k) {
        double v = 0.0;
        for (int idx = threadIdx.x; idx < NBLK; idx += NTHR)
            v += (double)ws[k * NBLK + idx];
        for (int o = 32; o > 0; o >>= 1) v += __shfl_down(v, o, 64);
        if ((threadIdx.x & 63) == 0) sm[k][threadIdx.x >> 6] = v;
    }
    __syncthreads();
    if (threadIdx.x == 0) {
        double r[NACC];
#pragma unroll
        for (int k = 0; k < NACC; ++k) {
            double s = 0.0;
            for (int w = 0; w < NTHR / 64; ++w) s += sm[k][w];
            r[k] = s;
        }
        const double Npix  = (double)NPIX;
        const double Ngrad = (double)BATCH * IMG_H * (IMG_W - 1);

        double total = r[0] / Npix;  // reconstruction L1
        double dice = (2.0 * r[1] + 1e-5) / (r[2] + r[3] + 1e-5);
        dice = fmin(fmax(dice, 0.0), 1.0);
        total += 0.3 * (-log(dice + 1e-8));
        total += 0.2 * 0.5 * ((r[4] + r[5]) / Ngrad);
        total += 0.2 * 0.5 * ((r[6] + r[7]) / Npix);

        out[0] = (float)fmax(total, 0.0);
    }
}

extern "C" void kernel_launch(void* const* d_in, const int* in_sizes, int n_in,
                              void* d_out, int out_size, void* d_ws, size_t ws_size,
                              hipStream_t stream) {
    const float* pred = (const float*)d_in[0];
    const float* tgt  = (const float*)d_in[1];
    float* out = (float*)d_out;
    float* ws  = (float*)d_ws;   // NACC*NBLK*4 = 32 KB

    morph_partials<<<NBLK, NTHR, 0, stream>>>(pred, tgt, ws);
    morph_final<<<1, NTHR, 0, stream>>>(ws, out);
}